// Round 3
// baseline (74.843 us; speedup 1.0000x reference)
//
#include <hip/hip_runtime.h>
#include <hip/hip_bf16.h>

#define B_ 256
#define S_ 512
#define H_ 300
#define NL_ 7
#define NT_ 640     // 10 waves: two 5-wave gather groups
#define GRP_ 320
#define NWAVE_ 10

// One block per batch row: gather+avg -> 3-layer MLP -> logp; last block
// (atomic counter) reduces the loss deterministically (fixed sum order).
__global__ __launch_bounds__(NT_) void dan_fused(
    const int* __restrict__ ids, const int* __restrict__ am,
    const int* __restrict__ labels, const int* __restrict__ drop,
    const float* __restrict__ emb,
    const float* __restrict__ W1, const float* __restrict__ b1,
    const float* __restrict__ W2, const float* __restrict__ b2,
    const float* __restrict__ W3, const float* __restrict__ b3,
    float* __restrict__ out, float* __restrict__ perloss,
    unsigned* __restrict__ cnt) {
  const int b = blockIdx.x, t = threadIdx.x;
  __shared__ int sid[S_];
  __shared__ float sred[H_];
  __shared__ float savg[H_];
  __shared__ float sh1[H_];
  __shared__ float sh2[H_];
  __shared__ float swred[8];
  __shared__ float snz;
  __shared__ float slog[NL_];

  // ---- phase 0: masked ids to LDS + drop_mask row sum ----
  if (t < S_) {
    int off = b * S_ + t;
    sid[t] = ids[off] * am[off];
    int dv = drop[off];
    for (int o = 32; o > 0; o >>= 1) dv += __shfl_down(dv, o, 64);
    if ((t & 63) == 0) swred[t >> 6] = (float)dv;
  }
  __syncthreads();
  if (t == 0) {
    float s2 = 0.f;
    for (int w = 0; w < 8; ++w) s2 += swred[w];
    snz = s2;
  }
  __syncthreads();

  // ---- phase 1: gather-sum. group g covers tokens [256g, 256g+256) ----
  const int g = (t >= GRP_) ? 1 : 0;
  const int lt = t - g * GRP_;
  float a0 = 0.f, a1 = 0.f, a2 = 0.f, a3 = 0.f;
  if (lt < H_) {
    const float* ep = emb + lt;
    const int s0 = g * (S_ / 2);
#pragma unroll 2
    for (int s = s0; s < s0 + S_ / 2; s += 8) {
      a0 += ep[sid[s] * H_];
      a1 += ep[sid[s + 1] * H_];
      a2 += ep[sid[s + 2] * H_];
      a3 += ep[sid[s + 3] * H_];
      a0 += ep[sid[s + 4] * H_];
      a1 += ep[sid[s + 5] * H_];
      a2 += ep[sid[s + 6] * H_];
      a3 += ep[sid[s + 7] * H_];
    }
  }
  if (g == 1 && lt < H_) sred[lt] = (a0 + a1) + (a2 + a3);
  __syncthreads();
  if (g == 0 && lt < H_)
    savg[lt] = ((a0 + a1) + (a2 + a3) + sred[lt]) / snz;
  __syncthreads();

  // ---- phase 2: MLP, one W-row per wave, shuffle-reduced dot ----
  const int wv = t >> 6;
  const int lane = t & 63;

  // h1 = relu(W1 @ avg + b1)
  for (int i = wv; i < H_; i += NWAVE_) {
    const float* row = W1 + i * H_;
    float d = row[lane] * savg[lane];
    d = fmaf(row[lane + 64], savg[lane + 64], d);
    d = fmaf(row[lane + 128], savg[lane + 128], d);
    d = fmaf(row[lane + 192], savg[lane + 192], d);
    if (lane < H_ - 256) d = fmaf(row[lane + 256], savg[lane + 256], d);
    for (int o = 32; o > 0; o >>= 1) d += __shfl_xor(d, o, 64);
    if (lane == 0) sh1[i] = fmaxf(d + b1[i], 0.f);
  }
  __syncthreads();

  // h2 = relu(W2 @ h1 + b2)
  for (int i = wv; i < H_; i += NWAVE_) {
    const float* row = W2 + i * H_;
    float d = row[lane] * sh1[lane];
    d = fmaf(row[lane + 64], sh1[lane + 64], d);
    d = fmaf(row[lane + 128], sh1[lane + 128], d);
    d = fmaf(row[lane + 192], sh1[lane + 192], d);
    if (lane < H_ - 256) d = fmaf(row[lane + 256], sh1[lane + 256], d);
    for (int o = 32; o > 0; o >>= 1) d += __shfl_xor(d, o, 64);
    if (lane == 0) sh2[i] = fmaxf(d + b2[i], 0.f);
  }
  __syncthreads();

  // logits = W3 @ h2 + b3  (7 rows, waves 0..6)
  if (wv < NL_) {
    const float* row = W3 + wv * H_;
    float d = row[lane] * sh2[lane];
    d = fmaf(row[lane + 64], sh2[lane + 64], d);
    d = fmaf(row[lane + 128], sh2[lane + 128], d);
    d = fmaf(row[lane + 192], sh2[lane + 192], d);
    if (lane < H_ - 256) d = fmaf(row[lane + 256], sh2[lane + 256], d);
    for (int o = 32; o > 0; o >>= 1) d += __shfl_xor(d, o, 64);
    if (lane == 0) {
      d += b3[wv];
      slog[wv] = d;
      out[1 + b * NL_ + wv] = d;
    }
  }
  __syncthreads();

  // ---- phase 3: log-softmax -> perloss[b] ----
  if (t == 0) {
    float m = slog[0];
    for (int c = 1; c < NL_; ++c) m = fmaxf(m, slog[c]);
    float se = 0.f;
    for (int c = 0; c < NL_; ++c) se += expf(slog[c] - m);
    int lab = labels[b];
    perloss[b] = slog[lab] - m - logf(se);
  }
  __syncthreads();

  // ---- phase 4: last block reduces loss (deterministic fixed order) ----
  if (t < 64) {
    unsigned old = 0;
    if (t == 0) {
      __threadfence();
      old = atomicAdd(cnt, 1u);
    }
    old = __shfl(old, 0, 64);
    if (old == B_ - 1) {
      __threadfence();
      float v = perloss[t] + perloss[t + 64] + perloss[t + 128] +
                perloss[t + 192];
      for (int o = 32; o > 0; o >>= 1) v += __shfl_xor(v, o, 64);
      if (t == 0) out[0] = -v * (1.0f / (float)B_);
    }
  }
}

extern "C" void kernel_launch(void* const* d_in, const int* in_sizes, int n_in,
                              void* d_out, int out_size, void* d_ws,
                              size_t ws_size, hipStream_t stream) {
  const int* ids = (const int*)d_in[0];
  const int* am = (const int*)d_in[1];
  const int* labels = (const int*)d_in[2];
  const int* drop = (const int*)d_in[3];
  const float* emb = (const float*)d_in[4];
  const float* W1 = (const float*)d_in[5];
  const float* b1 = (const float*)d_in[6];
  const float* W2 = (const float*)d_in[7];
  const float* b2 = (const float*)d_in[8];
  const float* W3 = (const float*)d_in[9];
  const float* b3 = (const float*)d_in[10];
  float* out = (float*)d_out;

  float* perloss = (float*)d_ws;           // [256]
  unsigned* cnt = (unsigned*)((char*)d_ws + B_ * sizeof(float));

  hipMemsetAsync(cnt, 0, sizeof(unsigned), stream);
  dan_fused<<<B_, NT_, 0, stream>>>(ids, am, labels, drop, emb, W1, b1, W2,
                                    b2, W3, b3, out, perloss, cnt);
}

// Round 4
// 58.747 us; speedup vs baseline: 1.2740x; 1.2740x over previous
//
#include <hip/hip_runtime.h>
#include <hip/hip_bf16.h>

#define B_ 256
#define S_ 512
#define H_ 300
#define NL_ 7
#define NT_ 320   // block threads (5 waves); 300 active for H-dim work
#define NCHUNK_ 8
#define SPER_ (S_ / NCHUNK_)   // 64

#define NGATHER_ (B_ * NCHUNK_)          // 2048 gather blocks
#define NTILE_ 10                        // ceil(300/32)
#define NTRANS_ (2 * NTILE_ * NTILE_)    // 200 transpose blocks (FIRST)

// ---------------- Kernel A: W1/W2 transpose (first) + masked gather --------
// blocks [0, NTRANS_): 32x32 tiled transpose of W1,W2 -> ws (finish fast,
// no tail). blocks [NTRANS_, NTRANS_+NGATHER_): embedding gather partials.
__global__ __launch_bounds__(NT_) void dan_gather_t(
    const int* __restrict__ ids, const int* __restrict__ am,
    const float* __restrict__ emb,
    const float* __restrict__ W1, const float* __restrict__ W2,
    float* __restrict__ partial, float* __restrict__ WT1,
    float* __restrict__ WT2) {
  const int bid = blockIdx.x;
  const int t = threadIdx.x;

  if (bid >= NTRANS_) {
    // ---- gather: 64-token chunk, plain (no compaction) ----
    const int gb = bid - NTRANS_;
    const int b = gb >> 3, c = gb & 7;
    __shared__ int sid[SPER_];
    if (t < SPER_) {
      int off = b * S_ + c * SPER_ + t;
      sid[t] = ids[off] * am[off];
    }
    __syncthreads();
    if (t < H_) {
      const float* ep = emb + t;
      float a0 = 0.f, a1 = 0.f, a2 = 0.f, a3 = 0.f;
#pragma unroll
      for (int s = 0; s < SPER_; s += 8) {
        a0 += ep[sid[s] * H_];
        a1 += ep[sid[s + 1] * H_];
        a2 += ep[sid[s + 2] * H_];
        a3 += ep[sid[s + 3] * H_];
        a0 += ep[sid[s + 4] * H_];
        a1 += ep[sid[s + 5] * H_];
        a2 += ep[sid[s + 6] * H_];
        a3 += ep[sid[s + 7] * H_];
      }
      partial[gb * H_ + t] = (a0 + a1) + (a2 + a3);
    }
  } else {
    // ---- transpose W1/W2 into ws (32x32 tiles, 320 threads as 32x10) ----
    int tid = bid;
    const float* src = (tid < NTILE_ * NTILE_) ? W1 : W2;
    float* dst = (tid < NTILE_ * NTILE_) ? WT1 : WT2;
    int tile = (tid < NTILE_ * NTILE_) ? tid : tid - NTILE_ * NTILE_;
    int by = (tile / NTILE_) * 32, bx = (tile % NTILE_) * 32;
    __shared__ float stile[32][33];
    int tx = t & 31, ty = t >> 5;  // 32 x 10
    for (int r = ty; r < 32; r += 10) {
      int row = by + r, col = bx + tx;
      if (row < H_ && col < H_) stile[r][tx] = src[row * H_ + col];
    }
    __syncthreads();
    for (int r = ty; r < 32; r += 10) {
      int row = bx + r, col = by + tx;
      if (row < H_ && col < H_) dst[row * H_ + col] = stile[tx][r];
    }
  }
}

// ---------------- Kernel B: partial-reduce + MLP + logp + fused loss -------
// grid B_, block NT_. WT1/WT2 transposed (coalesced). Last block (atomic
// counter) reduces loss in fixed order -> deterministic.
__global__ __launch_bounds__(NT_) void dan_mlp(
    const float* __restrict__ partial, const int* __restrict__ drop,
    const int* __restrict__ labels,
    const float* __restrict__ WT1, const float* __restrict__ b1,
    const float* __restrict__ WT2, const float* __restrict__ b2,
    const float* __restrict__ W3, const float* __restrict__ b3,
    float* __restrict__ out, float* __restrict__ perloss,
    unsigned* __restrict__ cnt) {
  const int b = blockIdx.x, t = threadIdx.x;
  __shared__ float savg[H_];
  __shared__ float sh[H_];
  __shared__ float swred[NT_ / 64];
  __shared__ float snz;
  __shared__ float slog[NL_];

  // nonzeros[b] = sum_s drop_mask[b,s]
  int nzp = 0;
  for (int s = t; s < S_; s += NT_) nzp += drop[b * S_ + s];
  for (int o = 32; o > 0; o >>= 1) nzp += __shfl_down(nzp, o, 64);
  if ((t & 63) == 0) swred[t >> 6] = (float)nzp;
  __syncthreads();
  if (t == 0) {
    float s = 0.f;
    for (int w = 0; w < NT_ / 64; ++w) s += swred[w];
    snz = s;
  }
  __syncthreads();

  if (t < H_) {
    float s = 0.f;
#pragma unroll
    for (int c = 0; c < NCHUNK_; ++c) s += partial[(b * NCHUNK_ + c) * H_ + t];
    savg[t] = s / snz;
  }
  __syncthreads();

  // h1 = relu(W1 @ avg + b1); WT1[j*H + i]: lanes read contiguous -> coalesced
  if (t < H_) {
    float acc = b1[t];
    const float* w = WT1 + t;
#pragma unroll 10
    for (int j = 0; j < H_; ++j) acc = fmaf(w[(size_t)j * H_], savg[j], acc);
    sh[t] = fmaxf(acc, 0.f);
  }
  __syncthreads();

  // h2 = relu(W2 @ h1 + b2)
  if (t < H_) {
    float acc = b2[t];
    const float* w = WT2 + t;
#pragma unroll 10
    for (int j = 0; j < H_; ++j) acc = fmaf(w[(size_t)j * H_], sh[j], acc);
    savg[t] = fmaxf(acc, 0.f);
  }
  __syncthreads();

  // logits = W3 @ h2 + b3 (7 small dots)
  if (t < NL_) {
    float acc = b3[t];
    const float* w = W3 + t * H_;
    for (int j = 0; j < H_; ++j) acc = fmaf(w[j], savg[j], acc);
    slog[t] = acc;
    out[1 + b * NL_ + t] = acc;
  }
  __syncthreads();

  if (t == 0) {
    float m = slog[0];
    for (int c = 1; c < NL_; ++c) m = fmaxf(m, slog[c]);
    float se = 0.f;
    for (int c = 0; c < NL_; ++c) se += expf(slog[c] - m);
    int lab = labels[b];
    perloss[b] = slog[lab] - m - logf(se);
  }
  __syncthreads();

  // fused deterministic loss: last block to arrive reduces in fixed order
  if (t < 64) {
    unsigned old = 0;
    if (t == 0) {
      __threadfence();
      old = atomicAdd(cnt, 1u);
    }
    old = __shfl(old, 0, 64);
    if (old == B_ - 1) {
      __threadfence();
      float v = perloss[t] + perloss[t + 64] + perloss[t + 128] +
                perloss[t + 192];
      for (int o = 32; o > 0; o >>= 1) v += __shfl_xor(v, o, 64);
      if (t == 0) out[0] = -v * (1.0f / (float)B_);
    }
  }
}

extern "C" void kernel_launch(void* const* d_in, const int* in_sizes, int n_in,
                              void* d_out, int out_size, void* d_ws,
                              size_t ws_size, hipStream_t stream) {
  const int* ids = (const int*)d_in[0];
  const int* am = (const int*)d_in[1];
  const int* labels = (const int*)d_in[2];
  const int* drop = (const int*)d_in[3];
  const float* emb = (const float*)d_in[4];
  const float* W1 = (const float*)d_in[5];
  const float* b1 = (const float*)d_in[6];
  const float* W2 = (const float*)d_in[7];
  const float* b2 = (const float*)d_in[8];
  const float* W3 = (const float*)d_in[9];
  const float* b3 = (const float*)d_in[10];
  float* out = (float*)d_out;

  float* partial = (float*)d_ws;                          // [2048][300]
  float* perloss = partial + (size_t)NGATHER_ * H_;       // [256]
  float* WT1 = perloss + B_;                              // [300][300]
  float* WT2 = WT1 + (size_t)H_ * H_;                     // [300][300]
  unsigned* cnt = (unsigned*)(WT2 + (size_t)H_ * H_);

  hipMemsetAsync(cnt, 0, sizeof(unsigned), stream);
  dan_gather_t<<<NTRANS_ + NGATHER_, NT_, 0, stream>>>(ids, am, emb, W1, W2,
                                                       partial, WT1, WT2);
  dan_mlp<<<B_, NT_, 0, stream>>>(partial, drop, labels, WT1, b1, WT2, b2, W3,
                                  b3, out, perloss, cnt);
}

// Round 5
// 46.706 us; speedup vs baseline: 1.6024x; 1.2578x over previous
//
#include <hip/hip_runtime.h>
#include <hip/hip_bf16.h>

#define B_ 256
#define S_ 512
#define H_ 300
#define NL_ 7
#define NT_ 320   // block threads (5 waves); 300 active for H-dim work
#define NCHUNK_ 4
#define SPER_ (S_ / NCHUNK_)   // 128 tokens per gather block
#define NGATHER_ (B_ * NCHUNK_)  // 1024

#define Q_ (H_ / 4)   // 75 float4 per row

__device__ __forceinline__ void f4add(float4& a, const float4 b) {
  a.x += b.x; a.y += b.y; a.z += b.z; a.w += b.w;
}

// ---------------- Kernel A: masked embedding gather (float4) ---------------
// grid NGATHER_, block NT_. Threads split as 4 token-subgroups x 75 f4-lanes:
// thread t -> subgroup grp=t/75 handles tokens 4*it+grp, float4 dq=t%75.
__global__ __launch_bounds__(NT_) void dan_gather(
    const int* __restrict__ ids, const int* __restrict__ am,
    const float* __restrict__ emb, float* __restrict__ partial) {
  const int gb = blockIdx.x;
  const int b = gb >> 2, c = gb & 3;
  const int t = threadIdx.x;
  __shared__ int sid[SPER_];
  __shared__ __align__(16) float sacc[4][H_];

  if (t < SPER_) {
    int off = b * S_ + c * SPER_ + t;
    sid[t] = ids[off] * am[off];
  }
  __syncthreads();

  if (t < H_) {
    const int grp = t / Q_;       // 0..3
    const int dq = t - grp * Q_;  // 0..74
    const float* ebase = emb + 4 * dq;
    float4 a0 = {0.f, 0.f, 0.f, 0.f}, a1 = {0.f, 0.f, 0.f, 0.f};
#pragma unroll 8
    for (int it = 0; it < SPER_ / 4; ++it) {  // 32 iterations
      int id = sid[4 * it + grp];
      const float4 v =
          *reinterpret_cast<const float4*>(ebase + (size_t)id * H_);
      if (it & 1) f4add(a1, v); else f4add(a0, v);
    }
    f4add(a0, a1);
    *reinterpret_cast<float4*>(&sacc[grp][4 * dq]) = a0;
  }
  __syncthreads();

  if (t < H_)
    partial[gb * H_ + t] =
        (sacc[0][t] + sacc[1][t]) + (sacc[2][t] + sacc[3][t]);
}

// ---------------- Kernel B: partial-reduce + 3-layer MLP + logp ------------
// grid B_, block NT_. Strided W rows read as float4 (16B-aligned: row=1200B);
// L1 keeps the 64-line wave working set, every line fully consumed.
__global__ __launch_bounds__(NT_) void dan_mlp(
    const float* __restrict__ partial, const int* __restrict__ drop,
    const int* __restrict__ labels,
    const float* __restrict__ W1, const float* __restrict__ b1,
    const float* __restrict__ W2, const float* __restrict__ b2,
    const float* __restrict__ W3, const float* __restrict__ b3,
    float* __restrict__ out, float* __restrict__ perloss) {
  const int b = blockIdx.x, t = threadIdx.x;
  __shared__ __align__(16) float savg[H_];
  __shared__ __align__(16) float sh[H_];
  __shared__ float swred[NT_ / 64];
  __shared__ float snz;
  __shared__ float slog[NL_];

  // nonzeros[b] = sum_s drop_mask[b,s]
  int nzp = 0;
  for (int s = t; s < S_; s += NT_) nzp += drop[b * S_ + s];
  for (int o = 32; o > 0; o >>= 1) nzp += __shfl_down(nzp, o, 64);
  if ((t & 63) == 0) swred[t >> 6] = (float)nzp;
  __syncthreads();
  if (t == 0) {
    float s = 0.f;
    for (int w = 0; w < NT_ / 64; ++w) s += swred[w];
    snz = s;
  }
  __syncthreads();

  if (t < H_) {
    float s = 0.f;
#pragma unroll
    for (int c = 0; c < NCHUNK_; ++c) s += partial[(b * NCHUNK_ + c) * H_ + t];
    savg[t] = s / snz;
  }
  __syncthreads();

  // h1 = relu(W1 @ avg + b1)
  if (t < H_) {
    const float4* w = reinterpret_cast<const float4*>(W1 + (size_t)t * H_);
    const float4* x = reinterpret_cast<const float4*>(savg);
    float4 a = {0.f, 0.f, 0.f, 0.f};
#pragma unroll 5
    for (int j = 0; j < Q_; ++j) {
      float4 wv = w[j], xv = x[j];
      a.x = fmaf(wv.x, xv.x, a.x);
      a.y = fmaf(wv.y, xv.y, a.y);
      a.z = fmaf(wv.z, xv.z, a.z);
      a.w = fmaf(wv.w, xv.w, a.w);
    }
    sh[t] = fmaxf(b1[t] + (a.x + a.y) + (a.z + a.w), 0.f);
  }
  __syncthreads();

  // h2 = relu(W2 @ h1 + b2)  (into savg; h1-phase reads done)
  if (t < H_) {
    const float4* w = reinterpret_cast<const float4*>(W2 + (size_t)t * H_);
    const float4* x = reinterpret_cast<const float4*>(sh);
    float4 a = {0.f, 0.f, 0.f, 0.f};
#pragma unroll 5
    for (int j = 0; j < Q_; ++j) {
      float4 wv = w[j], xv = x[j];
      a.x = fmaf(wv.x, xv.x, a.x);
      a.y = fmaf(wv.y, xv.y, a.y);
      a.z = fmaf(wv.z, xv.z, a.z);
      a.w = fmaf(wv.w, xv.w, a.w);
    }
    savg[t] = fmaxf(b2[t] + (a.x + a.y) + (a.z + a.w), 0.f);
  }
  __syncthreads();

  // logits = W3 @ h2 + b3
  if (t < NL_) {
    const float4* w = reinterpret_cast<const float4*>(W3 + (size_t)t * H_);
    const float4* x = reinterpret_cast<const float4*>(savg);
    float4 a = {0.f, 0.f, 0.f, 0.f};
#pragma unroll 5
    for (int j = 0; j < Q_; ++j) {
      float4 wv = w[j], xv = x[j];
      a.x = fmaf(wv.x, xv.x, a.x);
      a.y = fmaf(wv.y, xv.y, a.y);
      a.z = fmaf(wv.z, xv.z, a.z);
      a.w = fmaf(wv.w, xv.w, a.w);
    }
    float acc = b3[t] + (a.x + a.y) + (a.z + a.w);
    slog[t] = acc;
    out[1 + b * NL_ + t] = acc;
  }
  __syncthreads();

  if (t == 0) {
    float m = slog[0];
    for (int c = 1; c < NL_; ++c) m = fmaxf(m, slog[c]);
    float se = 0.f;
    for (int c = 0; c < NL_; ++c) se += expf(slog[c] - m);
    int lab = labels[b];
    perloss[b] = slog[lab] - m - logf(se);
  }
}

// ---------------- Kernel C: deterministic loss reduction -------------------
__global__ void dan_loss(const float* __restrict__ perloss,
                         float* __restrict__ out) {
  const int t = threadIdx.x;  // 256 threads
  float v = perloss[t];
  for (int o = 32; o > 0; o >>= 1) v += __shfl_down(v, o, 64);
  __shared__ float r[4];
  if ((t & 63) == 0) r[t >> 6] = v;
  __syncthreads();
  if (t == 0) out[0] = -(r[0] + r[1] + r[2] + r[3]) * (1.0f / B_);
}

extern "C" void kernel_launch(void* const* d_in, const int* in_sizes, int n_in,
                              void* d_out, int out_size, void* d_ws,
                              size_t ws_size, hipStream_t stream) {
  const int* ids = (const int*)d_in[0];
  const int* am = (const int*)d_in[1];
  const int* labels = (const int*)d_in[2];
  const int* drop = (const int*)d_in[3];
  const float* emb = (const float*)d_in[4];
  const float* W1 = (const float*)d_in[5];
  const float* b1 = (const float*)d_in[6];
  const float* W2 = (const float*)d_in[7];
  const float* b2 = (const float*)d_in[8];
  const float* W3 = (const float*)d_in[9];
  const float* b3 = (const float*)d_in[10];
  float* out = (float*)d_out;

  float* partial = (float*)d_ws;                     // [1024][300]
  float* perloss = partial + (size_t)NGATHER_ * H_;  // [256]

  dan_gather<<<NGATHER_, NT_, 0, stream>>>(ids, am, emb, partial);
  dan_mlp<<<B_, NT_, 0, stream>>>(partial, drop, labels, W1, b1, W2, b2, W3,
                                  b3, out, perloss);
  dan_loss<<<1, B_, 0, stream>>>(perloss, out);
}